// Round 11
// baseline (527.563 us; speedup 1.0000x reference)
//
#include <hip/hip_runtime.h>
#include <hip/hip_bf16.h>
#include <cstdint>
#include <cstddef>

#define SEQLEN 2048
#define NBATCH 2
#define NHEAD  16
#define HDIM   64
#define HID    1024
#define MROWS  4096   // row r = s*2 + b

typedef __bf16 bf16x8 __attribute__((ext_vector_type(8)));
typedef float f32x4 __attribute__((ext_vector_type(4)));
typedef unsigned short ushort8 __attribute__((ext_vector_type(8)));

#define MFMA16(a, b, c) __builtin_amdgcn_mfma_f32_16x16x32_bf16((a), (b), (c), 0, 0, 0)

#define GLOAD_LDS16(g, l)                                                        \
    __builtin_amdgcn_global_load_lds(                                            \
        (const __attribute__((address_space(1))) void*)(g),                      \
        (__attribute__((address_space(3))) void*)(l), 16, 0, 0)

#define SBAR() __builtin_amdgcn_s_barrier()
#define SCHED_FENCE() __builtin_amdgcn_sched_barrier(0)
#define WAIT_VMCNT(n) asm volatile("s_waitcnt vmcnt(" #n ")" ::: "memory")

static __device__ __forceinline__ unsigned int pack_bf16_pair(float lo, float hi) {
    unsigned short a = __builtin_bit_cast(unsigned short, (__bf16)lo);
    unsigned short b = __builtin_bit_cast(unsigned short, (__bf16)hi);
    return ((unsigned int)b << 16) | a;
}

// ---------------------------------------------------------------------------
// conv6: fp32 -> bf16 for {query,key,value,Wq,Wk,Wv} into scratch (attn area)
// ---------------------------------------------------------------------------
__global__ __launch_bounds__(256) void conv6(
    const float* __restrict__ s0, const float* __restrict__ s1, const float* __restrict__ s2,
    const float* __restrict__ s3, const float* __restrict__ s4, const float* __restrict__ s5,
    unsigned short* __restrict__ Sc)
{
    const int y = blockIdx.y;
    const float* src = (y == 0) ? s0 : (y == 1) ? s1 : (y == 2) ? s2
                     : (y == 3) ? s3 : (y == 4) ? s4 : s5;
    const size_t M1 = 1u << 20;
    unsigned short* dst = (y < 3) ? (Sc + (size_t)y * 4 * M1) : (Sc + 12 * M1 + (size_t)(y - 3) * M1);
    const size_t n = (y < 3) ? 4 * M1 : M1;

    const size_t i = ((size_t)blockIdx.x * 256 + threadIdx.x) * 8;
    if (i >= n) return;
    float4 f0 = *(const float4*)(src + i);
    float4 f1 = *(const float4*)(src + i + 4);
    ushort8 o;
    o[0] = __builtin_bit_cast(unsigned short, (__bf16)f0.x);
    o[1] = __builtin_bit_cast(unsigned short, (__bf16)f0.y);
    o[2] = __builtin_bit_cast(unsigned short, (__bf16)f0.z);
    o[3] = __builtin_bit_cast(unsigned short, (__bf16)f0.w);
    o[4] = __builtin_bit_cast(unsigned short, (__bf16)f1.x);
    o[5] = __builtin_bit_cast(unsigned short, (__bf16)f1.y);
    o[6] = __builtin_bit_cast(unsigned short, (__bf16)f1.z);
    o[7] = __builtin_bit_cast(unsigned short, (__bf16)f1.w);
    *(ushort8*)(dst + i) = o;
}

__global__ __launch_bounds__(256) void wconv(
    const float* __restrict__ Wo, unsigned short* __restrict__ Wob)
{
    const size_t i = ((size_t)blockIdx.x * 256 + threadIdx.x) * 8;
    float4 f0 = *(const float4*)(Wo + i);
    float4 f1 = *(const float4*)(Wo + i + 4);
    ushort8 o;
    o[0] = __builtin_bit_cast(unsigned short, (__bf16)f0.x);
    o[1] = __builtin_bit_cast(unsigned short, (__bf16)f0.y);
    o[2] = __builtin_bit_cast(unsigned short, (__bf16)f0.z);
    o[3] = __builtin_bit_cast(unsigned short, (__bf16)f0.w);
    o[4] = __builtin_bit_cast(unsigned short, (__bf16)f1.x);
    o[5] = __builtin_bit_cast(unsigned short, (__bf16)f1.y);
    o[6] = __builtin_bit_cast(unsigned short, (__bf16)f1.z);
    o[7] = __builtin_bit_cast(unsigned short, (__bf16)f1.w);
    *(ushort8*)(Wob + i) = o;
}

// ---------------------------------------------------------------------------
// Double-buffered bf16 GEMM (BK=32), R4-proven.
// ---------------------------------------------------------------------------
#define GSTAGE32(DSTARR, SRCP, k0v)                                              \
    _Pragma("unroll")                                                            \
    for (int c_ = 0; c_ < 2; ++c_) {                                             \
        const int row_ = (c_ << 6) + (threadIdx.x >> 2);                         \
        const unsigned short* gs_ = (SRCP) + (size_t)row_ * HID + (k0v)          \
            + ((((int)threadIdx.x & 3) ^ ((row_ >> 1) & 3)) << 3);               \
        GLOAD_LDS16(gs_, &(DSTARR)[((c_ << 6) + (((int)threadIdx.x >> 6) << 4)) * 32]); \
    }

#define GEMM_BODY(ApT, BpT)                                                      \
    GSTAGE32(As[0], ApT, 0);                                                     \
    GSTAGE32(Bs[0], BpT, 0);                                                     \
    for (int it = 0; it < 32; ++it) {                                            \
        SBAR();                                                                  \
        const int k1 = ((it + 1) & 31) << 5;                                     \
        GSTAGE32(As[(it + 1) & 1], ApT, k1);                                     \
        GSTAGE32(Bs[(it + 1) & 1], BpT, k1);                                     \
        WAIT_VMCNT(8);                                                           \
        SBAR();                                                                  \
        SCHED_FENCE();                                                           \
        const char* Ac = (const char*)As[it & 1];                                \
        const char* Bc = (const char*)Bs[it & 1];                                \
        bf16x8 a_h[4], b_h[4];                                                   \
        _Pragma("unroll")                                                        \
        for (int m = 0; m < 4; ++m) {                                            \
            const int row = wm * 64 + m * 16 + fr;                               \
            a_h[m] = *(const bf16x8*)(Ac + (row << 6) + ((fg ^ ((row >> 1) & 3)) << 4)); \
        }                                                                        \
        _Pragma("unroll")                                                        \
        for (int n = 0; n < 4; ++n) {                                            \
            const int row = wn * 64 + n * 16 + fr;                               \
            b_h[n] = *(const bf16x8*)(Bc + (row << 6) + ((fg ^ ((row >> 1) & 3)) << 4)); \
        }                                                                        \
        __builtin_amdgcn_s_setprio(1);                                           \
        _Pragma("unroll")                                                        \
        for (int m = 0; m < 4; ++m)                                              \
            _Pragma("unroll")                                                    \
            for (int n = 0; n < 4; ++n)                                          \
                acc[m][n] = MFMA16(a_h[m], b_h[n], acc[m][n]);                   \
        __builtin_amdgcn_s_setprio(0);                                           \
    }

__global__ __launch_bounds__(256) void qkv_gemm(
    const unsigned short* __restrict__ Sc,
    const float* __restrict__ bq, const float* __restrict__ bk, const float* __restrict__ bv,
    unsigned short* __restrict__ Qb, unsigned short* __restrict__ Kb, unsigned short* __restrict__ Vb)
{
    const int z = blockIdx.z;
    const size_t M1 = 1u << 20;
    const unsigned short* A = Sc + (size_t)z * 4 * M1;
    const unsigned short* B = Sc + 12 * M1 + (size_t)z * M1;
    const float* bias = (z == 0) ? bq : (z == 1) ? bk : bv;
    unsigned short* dst = (z == 0) ? Qb : (z == 1) ? Kb : Vb;

    __shared__ unsigned short As[2][128 * 32];
    __shared__ unsigned short Bs[2][128 * 32];

    const int t = threadIdx.x, lane = t & 63, w = t >> 6;
    const int wm = w >> 1, wn = w & 1;
    const int bm = blockIdx.x * 128, bn = blockIdx.y * 128;
    const int fr = lane & 15, fg = lane >> 4;

    const unsigned short* Ap = A + (size_t)bm * HID;
    const unsigned short* Bp = B + (size_t)bn * HID;

    f32x4 acc[4][4] = {};
    GEMM_BODY(Ap, Bp)

    #pragma unroll
    for (int n = 0; n < 4; ++n) {
        const int gc = bn + wn * 64 + n * 16 + fr;
        const float bb = bias[gc];
        #pragma unroll
        for (int m = 0; m < 4; ++m)
            #pragma unroll
            for (int r = 0; r < 4; ++r) {
                const int gr = bm + wm * 64 + m * 16 + fg * 4 + r;
                *(__bf16*)&dst[(size_t)gr * HID + gc] = (__bf16)(acc[m][n][r] + bb);
            }
    }
}

// ---------------------------------------------------------------------------
// vtrans: LDS-tiled transpose Vb [s2][h*64+d] -> Vt [b][h][d][s]
// ---------------------------------------------------------------------------
__global__ __launch_bounds__(256) void vtrans(
    const unsigned short* __restrict__ Vb, unsigned short* __restrict__ Vt)
{
    __shared__ unsigned short T[64][66];
    const int t = threadIdx.x;
    const int s0 = blockIdx.x * 64, h = blockIdx.y, b = blockIdx.z;

    {
        const int s_l = t >> 2, d0 = (t & 3) * 16;
        const unsigned short* src = Vb + (((size_t)(s0 + s_l) * 2 + b) << 10) + (h << 6) + d0;
        *(ushort8*)&T[s_l][d0]     = *(const ushort8*)src;
        *(ushort8*)&T[s_l][d0 + 8] = *(const ushort8*)(src + 8);
    }
    __syncthreads();
    {
        const int d_l = t >> 2, sc = (t & 3) * 16;
        ushort8 o0, o1;
        #pragma unroll
        for (int j = 0; j < 8; ++j) { o0[j] = T[sc + j][d_l]; o1[j] = T[sc + 8 + j][d_l]; }
        unsigned short* dst = Vt + (((size_t)((b << 4) + h) * 64 + d_l) << 11) + s0 + sc;
        *(ushort8*)dst       = o0;
        *(ushort8*)(dst + 8) = o1;
    }
}

// ---------------------------------------------------------------------------
// Register-prefetched K fragments (barrier-free attention core).
// Lane (fr,fg): q=fr, k = n*16 + fg*4 + r after swapped MFMA(K,Q).
// LOADK issues 16 global loads for tile ktv; compiler inserts the vmcnt wait
// at first use (waiting on OLDER loads never drains YOUNGER stores).
// ---------------------------------------------------------------------------
#define LOADK(DST, ktv)                                                          \
    _Pragma("unroll")                                                            \
    for (int n_ = 0; n_ < 8; ++n_) {                                             \
        const unsigned short* kr_ = kbase + ((size_t)((((ktv) & 15) << 7) + (n_ << 4)) << 11); \
        DST[n_][0] = *(const bf16x8*)kr_;                                        \
        DST[n_][1] = *(const bf16x8*)(kr_ + 32);                                 \
    }

// ---------------------------------------------------------------------------
// attn_pv: flash-style one pass; p~=exp2(s*c); O scaled by 1/sum at end;
// li=-log2(sum) parked in attn[b,h,q,0]. Zero barriers.
// ---------------------------------------------------------------------------
#define PV_BODY(KF, ktv)                                                         \
    {                                                                            \
        f32x4 s_[8] = {};                                                        \
        __builtin_amdgcn_s_setprio(1);                                           \
        _Pragma("unroll")                                                        \
        for (int n = 0; n < 8; ++n) {                                            \
            s_[n] = MFMA16(KF[n][0], qf[0], s_[n]);                              \
            s_[n] = MFMA16(KF[n][1], qf[1], s_[n]);                              \
        }                                                                        \
        __builtin_amdgcn_s_setprio(0);                                           \
        float a = 0.f;                                                           \
        _Pragma("unroll")                                                        \
        for (int n = 0; n < 8; ++n) {                                            \
            f32x4 p;                                                             \
            _Pragma("unroll")                                                    \
            for (int r = 0; r < 4; ++r)                                          \
                p[r] = exp2f(s_[n][r] * c_exp);                                  \
            a += (p[0] + p[1]) + (p[2] + p[3]);                                  \
            uint2 pk;                                                            \
            pk.x = pack_bf16_pair(p[0], p[1]);                                   \
            pk.y = pack_bf16_pair(p[2], p[3]);                                   \
            *(uint2*)(Plc + (fr << 8) + (((n << 5) | (fg << 3)) ^ rxl)) = pk;    \
        }                                                                        \
        lsum += a;                                                               \
        __builtin_amdgcn_s_setprio(1);                                           \
        _Pragma("unroll")                                                        \
        for (int kk2 = 0; kk2 < 4; ++kk2) {                                      \
            bf16x8 pa = *(const bf16x8*)(Plc + (fr << 8) + (((kk2 << 6) | fg16) ^ rxl)); \
            _Pragma("unroll")                                                    \
            for (int n2 = 0; n2 < 4; ++n2) {                                     \
                bf16x8 vf = *(const bf16x8*)(vb0 + (((size_t)n2 << 4) << 11) + ((ktv) << 7) + (kk2 << 5)); \
                oacc[n2] = MFMA16(pa, vf, oacc[n2]);                             \
            }                                                                    \
        }                                                                        \
        __builtin_amdgcn_s_setprio(0);                                           \
    }

__global__ __launch_bounds__(256) void attn_pv(
    const unsigned short* __restrict__ Qb, const unsigned short* __restrict__ Kb,
    const unsigned short* __restrict__ Vt, float* __restrict__ attn_out,
    unsigned short* __restrict__ Hb)
{
    __shared__ unsigned short Pl[4][16 * 128];   // 16 KB, per-wave 16x128 bf16

    const int flat = blockIdx.x;                 // 0..1023
    const int nf = (flat & 7) * 128 + (flat >> 3);
    const int qblk = nf & 31, h = (nf >> 5) & 15, b = nf >> 9;

    const int t = threadIdx.x, lane = t & 63, w = t >> 6;
    const int fr = lane & 15, fg = lane >> 4;
    const int fg4 = fg << 2, fg16 = fg << 4;
    const int qbase = qblk * 64 + w * 16;
    const float c_exp = 0.18033688011112042f;    // log2(e)/8

    bf16x8 qf[2];
    {
        const unsigned short* qp = Qb + (((size_t)(qbase + fr) * 2 + b) << 10) + (h << 6);
        qf[0] = *(const bf16x8*)(qp + (fg << 3));
        qf[1] = *(const bf16x8*)(qp + 32 + (fg << 3));
    }

    const unsigned short* kbase = Kb + (((size_t)fr * 2 + b) << 10) + (h << 6) + (fg << 3);
    const size_t vhead = (size_t)((b << 4) + h) << 6;
    const unsigned short* vb0 = Vt + ((vhead + fr) << 11) + (fg << 3);

    char* Plc = (char*)&Pl[w][0];
    const int rxl = (fr & 7) << 4;

    float lsum = 0.f;
    f32x4 oacc[4] = {};

    bf16x8 ka[8][2], kb2[8][2];
    LOADK(ka, 0);
    for (int kt = 0; kt < 16; kt += 2) {
        LOADK(kb2, kt + 1);
        SCHED_FENCE();                            // loads issue before body
        PV_BODY(ka, kt);
        LOADK(ka, kt + 2);
        SCHED_FENCE();
        PV_BODY(kb2, kt + 1);
    }

    float v = lsum;
    v += __shfl_xor(v, 16);
    v += __shfl_xor(v, 32);
    const float inv = 1.f / v;
    const float li = -__log2f(v);

    float* attnB = attn_out + ((size_t)((b << 4) + h) << 22);
    if (fg == 0)
        attnB[(size_t)(qbase + fr) << 11] = li;   // li parked in attn[.., q, 0]

    float iq[4];
    #pragma unroll
    for (int r = 0; r < 4; ++r) iq[r] = __shfl(inv, fg4 + r);

    #pragma unroll
    for (int n2 = 0; n2 < 4; ++n2)
        #pragma unroll
        for (int r = 0; r < 4; ++r) {
            const int q = qbase + fg4 + r;
            *(__bf16*)&Hb[(((size_t)q * 2 + b) << 10) + (h << 6) + (n2 << 4) + fr] =
                (__bf16)(oacc[n2][r] * iq[r]);
        }
}

// ---------------------------------------------------------------------------
// tail_fused: blocks [0,1024) = attn_store (barrier-free streaming writer,
// reg-prefetched K, reads li from attn[b,h,q,0]); blocks [1024,1280) =
// out_proj (R4 GEMM, reads Wob from the dead Vt region).
// ---------------------------------------------------------------------------
#define ST_BODY(KF, ktv)                                                         \
    {                                                                            \
        f32x4 s_[8] = {};                                                        \
        __builtin_amdgcn_s_setprio(1);                                           \
        _Pragma("unroll")                                                        \
        for (int n = 0; n < 8; ++n) {                                            \
            s_[n] = MFMA16(KF[n][0], qf[0], s_[n]);                              \
            s_[n] = MFMA16(KF[n][1], qf[1], s_[n]);                              \
        }                                                                        \
        __builtin_amdgcn_s_setprio(0);                                           \
        float* ab = attnB + ((size_t)(qbase + fr) << 11) + ((ktv) << 7) + fg4;   \
        _Pragma("unroll")                                                        \
        for (int n = 0; n < 8; ++n) {                                            \
            f32x4 p;                                                             \
            _Pragma("unroll")                                                    \
            for (int r = 0; r < 4; ++r)                                          \
                p[r] = exp2f(__builtin_fmaf(s_[n][r], c_exp, li));               \
            *(f32x4*)(ab + (n << 4)) = p;                                        \
        }                                                                        \
    }

__global__ __launch_bounds__(256) void tail_fused(
    const unsigned short* __restrict__ Qb, const unsigned short* __restrict__ Kb,
    float* __restrict__ attn_out,
    const unsigned short* __restrict__ Hb, const unsigned short* __restrict__ Wob,
    const float* __restrict__ bo, float* __restrict__ out)
{
    if (blockIdx.x < 1024) {
        // ----------------- attn_store -----------------
        const int flat = blockIdx.x;
        const int nf = (flat & 7) * 128 + (flat >> 3);
        const int qblk = nf & 31, h = (nf >> 5) & 15, b = nf >> 9;

        const int t = threadIdx.x, lane = t & 63, w = t >> 6;
        const int fr = lane & 15, fg = lane >> 4;
        const int fg4 = fg << 2;
        const int qbase = qblk * 64 + w * 16;
        const float c_exp = 0.18033688011112042f;

        bf16x8 qf[2];
        {
            const unsigned short* qp = Qb + (((size_t)(qbase + fr) * 2 + b) << 10) + (h << 6);
            qf[0] = *(const bf16x8*)(qp + (fg << 3));
            qf[1] = *(const bf16x8*)(qp + 32 + (fg << 3));
        }

        const unsigned short* kbase = Kb + (((size_t)fr * 2 + b) << 10) + (h << 6) + (fg << 3);
        float* attnB = attn_out + ((size_t)((b << 4) + h) << 22);
        const float li = attnB[(size_t)(qbase + fr) << 11];

        bf16x8 ka[8][2], kb2[8][2];
        LOADK(ka, 0);
        for (int kt = 0; kt < 16; kt += 2) {
            LOADK(kb2, kt + 1);
            SCHED_FENCE();
            ST_BODY(ka, kt);
            LOADK(ka, kt + 2);
            SCHED_FENCE();
            ST_BODY(kb2, kt + 1);
        }
    } else {
        // ----------------- out_proj -----------------
        __shared__ unsigned short As[2][128 * 32];
        __shared__ unsigned short Bs[2][128 * 32];

        const int idx = blockIdx.x - 1024;       // 0..255
        const int t = threadIdx.x, lane = t & 63, w = t >> 6;
        const int wm = w >> 1, wn = w & 1;
        const int bm = (idx & 31) * 128, bn = (idx >> 5) * 128;
        const int fr = lane & 15, fg = lane >> 4;

        const unsigned short* Ap = Hb + (size_t)bm * HID;
        const unsigned short* Bp = Wob + (size_t)bn * HID;

        f32x4 acc[4][4] = {};
        GEMM_BODY(Ap, Bp)

        #pragma unroll
        for (int n = 0; n < 4; ++n) {
            const int gc = bn + wn * 64 + n * 16 + fr;
            const float bb = bo[gc];
            #pragma unroll
            for (int m = 0; m < 4; ++m)
                #pragma unroll
                for (int r = 0; r < 4; ++r) {
                    const int gr = bm + wm * 64 + m * 16 + fg * 4 + r;
                    out[(size_t)gr * HID + gc] = acc[m][n][r] + bb;
                }
        }
    }
}

// ---------------------------------------------------------------------------
extern "C" void kernel_launch(void* const* d_in, const int* in_sizes, int n_in,
                              void* d_out, int out_size, void* d_ws, size_t ws_size,
                              hipStream_t stream)
{
    (void)in_sizes; (void)n_in; (void)out_size;

    const float* query = (const float*)d_in[0];
    const float* key   = (const float*)d_in[1];
    const float* value = (const float*)d_in[2];
    const float* bq    = (const float*)d_in[4];
    const float* bk    = (const float*)d_in[6];
    const float* bv    = (const float*)d_in[8];
    const float* Wo    = (const float*)d_in[9];
    const float* bo    = (const float*)d_in[10];

    float* out0 = (float*)d_out;
    float* attn = out0 + (size_t)MROWS * HID;

    if (ws_size < (size_t)32 * 1024 * 1024) return;
    const size_t nbuf = (size_t)MROWS * HID;            // 4M bf16 = 8MB
    unsigned short* Qb = (unsigned short*)d_ws;         // [0, 8MB)
    unsigned short* Kb = Qb + nbuf;                     // [8, 16MB)
    unsigned short* Vb = Kb + nbuf;                     // [16, 24MB) -> Hb after vtrans
    unsigned short* Vt = Vb + nbuf;                     // [24, 32MB) -> Wob after attn_pv
    unsigned short* Hb = Vb;
    unsigned short* Wob = Vt;                           // Vt dead after attn_pv

    unsigned short* Sc = (unsigned short*)attn;         // scratch inside attn area (30MB)

    conv6<<<dim3(2048, 6), 256, 0, stream>>>(query, key, value,
                                             (const float*)d_in[3], (const float*)d_in[5],
                                             (const float*)d_in[7], Sc);
    qkv_gemm<<<dim3(32, 8, 3), 256, 0, stream>>>(Sc, bq, bk, bv, Qb, Kb, Vb);
    vtrans<<<dim3(32, NHEAD, NBATCH), 256, 0, stream>>>(Vb, Vt);
    attn_pv<<<dim3(1024), 256, 0, stream>>>(Qb, Kb, Vt, attn, Hb);
    wconv<<<dim3(512), 256, 0, stream>>>(Wo, Wob);
    tail_fused<<<dim3(1280), 256, 0, stream>>>(Qb, Kb, attn, Hb, Wob, bo, out0);
}

// Round 12
// 319.003 us; speedup vs baseline: 1.6538x; 1.6538x over previous
//
#include <hip/hip_runtime.h>
#include <hip/hip_bf16.h>
#include <cstdint>
#include <cstddef>

#define SEQLEN 2048
#define NBATCH 2
#define NHEAD  16
#define HDIM   64
#define HID    1024
#define MROWS  4096   // row r = s*2 + b

typedef __bf16 bf16x8 __attribute__((ext_vector_type(8)));
typedef float f32x4 __attribute__((ext_vector_type(4)));
typedef unsigned short ushort8 __attribute__((ext_vector_type(8)));

#define MFMA16(a, b, c) __builtin_amdgcn_mfma_f32_16x16x32_bf16((a), (b), (c), 0, 0, 0)

#define GLOAD_LDS16(g, l)                                                        \
    __builtin_amdgcn_global_load_lds(                                            \
        (const __attribute__((address_space(1))) void*)(g),                      \
        (__attribute__((address_space(3))) void*)(l), 16, 0, 0)

#define SBAR() __builtin_amdgcn_s_barrier()
#define SCHED_FENCE() __builtin_amdgcn_sched_barrier(0)
#define WAIT_VMCNT(n) asm volatile("s_waitcnt vmcnt(" #n ")" ::: "memory")

static __device__ __forceinline__ unsigned int pack_bf16_pair(float lo, float hi) {
    unsigned short a = __builtin_bit_cast(unsigned short, (__bf16)lo);
    unsigned short b = __builtin_bit_cast(unsigned short, (__bf16)hi);
    return ((unsigned int)b << 16) | a;
}

// ---------------------------------------------------------------------------
// conv6: fp32 -> bf16 for {query,key,value,Wq,Wk,Wv} into scratch (attn area)
// ---------------------------------------------------------------------------
__global__ __launch_bounds__(256) void conv6(
    const float* __restrict__ s0, const float* __restrict__ s1, const float* __restrict__ s2,
    const float* __restrict__ s3, const float* __restrict__ s4, const float* __restrict__ s5,
    unsigned short* __restrict__ Sc)
{
    const int y = blockIdx.y;
    const float* src = (y == 0) ? s0 : (y == 1) ? s1 : (y == 2) ? s2
                     : (y == 3) ? s3 : (y == 4) ? s4 : s5;
    const size_t M1 = 1u << 20;
    unsigned short* dst = (y < 3) ? (Sc + (size_t)y * 4 * M1) : (Sc + 12 * M1 + (size_t)(y - 3) * M1);
    const size_t n = (y < 3) ? 4 * M1 : M1;

    const size_t i = ((size_t)blockIdx.x * 256 + threadIdx.x) * 8;
    if (i >= n) return;
    float4 f0 = *(const float4*)(src + i);
    float4 f1 = *(const float4*)(src + i + 4);
    ushort8 o;
    o[0] = __builtin_bit_cast(unsigned short, (__bf16)f0.x);
    o[1] = __builtin_bit_cast(unsigned short, (__bf16)f0.y);
    o[2] = __builtin_bit_cast(unsigned short, (__bf16)f0.z);
    o[3] = __builtin_bit_cast(unsigned short, (__bf16)f0.w);
    o[4] = __builtin_bit_cast(unsigned short, (__bf16)f1.x);
    o[5] = __builtin_bit_cast(unsigned short, (__bf16)f1.y);
    o[6] = __builtin_bit_cast(unsigned short, (__bf16)f1.z);
    o[7] = __builtin_bit_cast(unsigned short, (__bf16)f1.w);
    *(ushort8*)(dst + i) = o;
}

__global__ __launch_bounds__(256) void wconv(
    const float* __restrict__ Wo, unsigned short* __restrict__ Wob)
{
    const size_t i = ((size_t)blockIdx.x * 256 + threadIdx.x) * 8;
    float4 f0 = *(const float4*)(Wo + i);
    float4 f1 = *(const float4*)(Wo + i + 4);
    ushort8 o;
    o[0] = __builtin_bit_cast(unsigned short, (__bf16)f0.x);
    o[1] = __builtin_bit_cast(unsigned short, (__bf16)f0.y);
    o[2] = __builtin_bit_cast(unsigned short, (__bf16)f0.z);
    o[3] = __builtin_bit_cast(unsigned short, (__bf16)f0.w);
    o[4] = __builtin_bit_cast(unsigned short, (__bf16)f1.x);
    o[5] = __builtin_bit_cast(unsigned short, (__bf16)f1.y);
    o[6] = __builtin_bit_cast(unsigned short, (__bf16)f1.z);
    o[7] = __builtin_bit_cast(unsigned short, (__bf16)f1.w);
    *(ushort8*)(Wob + i) = o;
}

// ---------------------------------------------------------------------------
// Double-buffered bf16 GEMM (BK=32): per-iter {sbar; stage(next); vmcnt(8);
// sbar; frag reads + 16 MFMA}. LDS 32 KB. Row swizzle: slot ^= (row>>1)&3.
// ---------------------------------------------------------------------------
#define GSTAGE32(DSTARR, SRCP, k0v)                                              \
    _Pragma("unroll")                                                            \
    for (int c_ = 0; c_ < 2; ++c_) {                                             \
        const int row_ = (c_ << 6) + (threadIdx.x >> 2);                         \
        const unsigned short* gs_ = (SRCP) + (size_t)row_ * HID + (k0v)          \
            + ((((int)threadIdx.x & 3) ^ ((row_ >> 1) & 3)) << 3);               \
        GLOAD_LDS16(gs_, &(DSTARR)[((c_ << 6) + (((int)threadIdx.x >> 6) << 4)) * 32]); \
    }

#define GEMM_BODY(ApT, BpT)                                                      \
    GSTAGE32(As[0], ApT, 0);                                                     \
    GSTAGE32(Bs[0], BpT, 0);                                                     \
    for (int it = 0; it < 32; ++it) {                                            \
        SBAR();                                                                  \
        const int k1 = ((it + 1) & 31) << 5;                                     \
        GSTAGE32(As[(it + 1) & 1], ApT, k1);                                     \
        GSTAGE32(Bs[(it + 1) & 1], BpT, k1);                                     \
        WAIT_VMCNT(8);                                                           \
        SBAR();                                                                  \
        SCHED_FENCE();                                                           \
        const char* Ac = (const char*)As[it & 1];                                \
        const char* Bc = (const char*)Bs[it & 1];                                \
        bf16x8 a_h[4], b_h[4];                                                   \
        _Pragma("unroll")                                                        \
        for (int m = 0; m < 4; ++m) {                                            \
            const int row = wm * 64 + m * 16 + fr;                               \
            a_h[m] = *(const bf16x8*)(Ac + (row << 6) + ((fg ^ ((row >> 1) & 3)) << 4)); \
        }                                                                        \
        _Pragma("unroll")                                                        \
        for (int n = 0; n < 4; ++n) {                                            \
            const int row = wn * 64 + n * 16 + fr;                               \
            b_h[n] = *(const bf16x8*)(Bc + (row << 6) + ((fg ^ ((row >> 1) & 3)) << 4)); \
        }                                                                        \
        __builtin_amdgcn_s_setprio(1);                                           \
        _Pragma("unroll")                                                        \
        for (int m = 0; m < 4; ++m)                                              \
            _Pragma("unroll")                                                    \
            for (int n = 0; n < 4; ++n)                                          \
                acc[m][n] = MFMA16(a_h[m], b_h[n], acc[m][n]);                   \
        __builtin_amdgcn_s_setprio(0);                                           \
    }

__global__ __launch_bounds__(256) void qkv_gemm(
    const unsigned short* __restrict__ Sc,
    const float* __restrict__ bq, const float* __restrict__ bk, const float* __restrict__ bv,
    unsigned short* __restrict__ Qb, unsigned short* __restrict__ Kb, unsigned short* __restrict__ Vb)
{
    const int z = blockIdx.z;
    const size_t M1 = 1u << 20;
    const unsigned short* A = Sc + (size_t)z * 4 * M1;
    const unsigned short* B = Sc + 12 * M1 + (size_t)z * M1;
    const float* bias = (z == 0) ? bq : (z == 1) ? bk : bv;
    unsigned short* dst = (z == 0) ? Qb : (z == 1) ? Kb : Vb;

    __shared__ unsigned short As[2][128 * 32];
    __shared__ unsigned short Bs[2][128 * 32];

    const int t = threadIdx.x, lane = t & 63, w = t >> 6;
    const int wm = w >> 1, wn = w & 1;
    const int bm = blockIdx.x * 128, bn = blockIdx.y * 128;
    const int fr = lane & 15, fg = lane >> 4;

    const unsigned short* Ap = A + (size_t)bm * HID;
    const unsigned short* Bp = B + (size_t)bn * HID;

    f32x4 acc[4][4] = {};
    GEMM_BODY(Ap, Bp)

    #pragma unroll
    for (int n = 0; n < 4; ++n) {
        const int gc = bn + wn * 64 + n * 16 + fr;
        const float bb = bias[gc];
        #pragma unroll
        for (int m = 0; m < 4; ++m)
            #pragma unroll
            for (int r = 0; r < 4; ++r) {
                const int gr = bm + wm * 64 + m * 16 + fg * 4 + r;
                *(__bf16*)&dst[(size_t)gr * HID + gc] = (__bf16)(acc[m][n][r] + bb);
            }
    }
}

// ---------------------------------------------------------------------------
// vtrans: LDS-tiled transpose Vb [s2][h*64+d] -> Vt [b][h][d][s]
// ---------------------------------------------------------------------------
__global__ __launch_bounds__(256) void vtrans(
    const unsigned short* __restrict__ Vb, unsigned short* __restrict__ Vt)
{
    __shared__ unsigned short T[64][66];
    const int t = threadIdx.x;
    const int s0 = blockIdx.x * 64, h = blockIdx.y, b = blockIdx.z;

    {
        const int s_l = t >> 2, d0 = (t & 3) * 16;
        const unsigned short* src = Vb + (((size_t)(s0 + s_l) * 2 + b) << 10) + (h << 6) + d0;
        *(ushort8*)&T[s_l][d0]     = *(const ushort8*)src;
        *(ushort8*)&T[s_l][d0 + 8] = *(const ushort8*)(src + 8);
    }
    __syncthreads();
    {
        const int d_l = t >> 2, sc = (t & 3) * 16;
        ushort8 o0, o1;
        #pragma unroll
        for (int j = 0; j < 8; ++j) { o0[j] = T[sc + j][d_l]; o1[j] = T[sc + 8 + j][d_l]; }
        unsigned short* dst = Vt + (((size_t)((b << 4) + h) * 64 + d_l) << 11) + s0 + sc;
        *(ushort8*)dst       = o0;
        *(ushort8*)(dst + 8) = o1;
    }
}

// ---------------------------------------------------------------------------
// attn2: swapped-QK^T fused attention, double-buffered K staging with counted
// vmcnt. Lane (fr,fg): q=fr, k=16n+fg*4+r. LDS 48 KB (3 blocks/CU).
// ---------------------------------------------------------------------------
#define STAGE_K(ktv, bufsel)                                                     \
    {                                                                            \
        const int kti_ = (ktv) & 15;                                             \
        _Pragma("unroll")                                                        \
        for (int c_ = 0; c_ < 4; ++c_) {                                         \
            const int rb_ = (w << 5) + (c_ << 3);                                \
            const int rl_ = rb_ + (lane >> 3);                                   \
            const unsigned short* ks_ = Kb + (((size_t)((kti_ << 7) + rl_) * 2 + b) << 10) \
                + (h << 6) + (((lane & 7) ^ (rl_ & 7)) << 3);                    \
            GLOAD_LDS16(ks_, &Ks[bufsel][rb_ * 64]);                             \
        }                                                                        \
    }

__global__ __launch_bounds__(256) void attn2(
    const unsigned short* __restrict__ Qb, const unsigned short* __restrict__ Kb,
    const unsigned short* __restrict__ Vt, float* __restrict__ attn_out,
    unsigned short* __restrict__ Hb)
{
    __shared__ unsigned short Ks[2][128 * 64];   // 32 KB double-buffered K
    __shared__ unsigned short Pl[4][16 * 128];   // 16 KB, per-wave 16x128 bf16

    const int flat = blockIdx.x + (blockIdx.y << 4) + (blockIdx.z << 8);
    const int nf = (flat & 7) * 64 + (flat >> 3);
    const int qblk = nf & 15, h = (nf >> 4) & 15, b = nf >> 8;

    const int t = threadIdx.x, lane = t & 63, w = t >> 6;
    const int fr = lane & 15, fg = lane >> 4;
    const int fg4 = fg << 2, fg16 = fg << 4;
    const int qbase = qblk * 128 + w * 32;
    const float c_exp = 0.18033688011112042f;    // log2(e)/8

    bf16x8 qf[2][2];
    #pragma unroll
    for (int mi = 0; mi < 2; ++mi) {
        const int q = qbase + mi * 16 + fr;
        const unsigned short* qp = Qb + (((size_t)q * 2 + b) << 10) + (h << 6);
        qf[mi][0] = *(const bf16x8*)(qp + (fg << 3));
        qf[mi][1] = *(const bf16x8*)(qp + 32 + (fg << 3));
    }

    char* Plc = (char*)&Pl[w][0];
    float lsum[2] = {0.f, 0.f};

    // ---------------- pass 1: row sums ----------------
    STAGE_K(0, 0);
    for (int kt = 0; kt < 16; ++kt) {
        SBAR();
        STAGE_K(kt + 1, (kt + 1) & 1);
        WAIT_VMCNT(4);
        SBAR();
        SCHED_FENCE();

        const char* Kc = (const char*)Ks[kt & 1];
        f32x4 s_[2][8] = {};
        __builtin_amdgcn_s_setprio(1);
        #pragma unroll
        for (int n = 0; n < 8; ++n) {
            const int row = (n << 4) + fr;
            const int rx = (row & 7) << 4;
            #pragma unroll
            for (int kk = 0; kk < 2; ++kk) {
                bf16x8 kf = *(const bf16x8*)(Kc + (row << 7) + (((kk << 6) | fg16) ^ rx));
                s_[0][n] = MFMA16(kf, qf[0][kk], s_[0][n]);
                s_[1][n] = MFMA16(kf, qf[1][kk], s_[1][n]);
            }
        }
        __builtin_amdgcn_s_setprio(0);

        #pragma unroll
        for (int mi = 0; mi < 2; ++mi) {
            float a = 0.f;
            #pragma unroll
            for (int n = 0; n < 8; ++n)
                #pragma unroll
                for (int r = 0; r < 4; ++r)
                    a += exp2f(s_[mi][n][r] * c_exp);
            lsum[mi] += a;
        }
    }

    float li[2];
    #pragma unroll
    for (int mi = 0; mi < 2; ++mi) {
        float v = lsum[mi];
        v += __shfl_xor(v, 16);
        v += __shfl_xor(v, 32);
        li[mi] = -__log2f(v);                    // fold 1/sum into exponent
    }

    f32x4 oacc[2][4] = {};
    float* attnB = attn_out + ((size_t)((b << 4) + h) << 22);
    const size_t vhead = (size_t)((b << 4) + h) << 6;

    // ---------------- pass 2 ----------------
    // pass 1's final STAGE_K already put kt=0 into Ks[0].
    for (int kt = 0; kt < 16; ++kt) {
        SBAR();
        STAGE_K(kt + 1, (kt + 1) & 1);
        WAIT_VMCNT(4);
        SBAR();
        SCHED_FENCE();

        const char* Kc = (const char*)Ks[kt & 1];
        f32x4 s_[2][8] = {};
        __builtin_amdgcn_s_setprio(1);
        #pragma unroll
        for (int n = 0; n < 8; ++n) {
            const int row = (n << 4) + fr;
            const int rx = (row & 7) << 4;
            #pragma unroll
            for (int kk = 0; kk < 2; ++kk) {
                bf16x8 kf = *(const bf16x8*)(Kc + (row << 7) + (((kk << 6) | fg16) ^ rx));
                s_[0][n] = MFMA16(kf, qf[0][kk], s_[0][n]);
                s_[1][n] = MFMA16(kf, qf[1][kk], s_[1][n]);
            }
        }
        __builtin_amdgcn_s_setprio(0);

        const int rxl = (fr & 7) << 4;
        #pragma unroll
        for (int mi = 0; mi < 2; ++mi) {
            // p = 2^(s*c + log2(inv)); NT store to attn; packed b64 -> Pl
            float* ab = attnB + ((size_t)(qbase + (mi << 4) + fr) << 11) + (kt << 7) + fg4;
            #pragma unroll
            for (int n = 0; n < 8; ++n) {
                f32x4 p;
                #pragma unroll
                for (int r = 0; r < 4; ++r)
                    p[r] = exp2f(__builtin_fmaf(s_[mi][n][r], c_exp, li[mi]));
                __builtin_nontemporal_store(p, (f32x4*)(ab + (n << 4)));
                uint2 pk;
                pk.x = pack_bf16_pair(p[0], p[1]);
                pk.y = pack_bf16_pair(p[2], p[3]);
                *(uint2*)(Plc + (fr << 8) + (((n << 5) | (fg << 3)) ^ rxl)) = pk;
            }
            asm volatile("s_waitcnt lgkmcnt(0)" ::: "memory");
            SCHED_FENCE();

            // PV (this mi): oacc[mi] += P(16x128) @ V(128x64)
            __builtin_amdgcn_s_setprio(1);
            #pragma unroll
            for (int kk2 = 0; kk2 < 4; ++kk2) {
                bf16x8 pa = *(const bf16x8*)(Plc + (fr << 8) + (((kk2 << 6) | fg16) ^ rxl));
                #pragma unroll
                for (int n2 = 0; n2 < 4; ++n2) {
                    bf16x8 vf = *(const bf16x8*)(Vt + ((vhead + (n2 << 4) + fr) << 11)
                                                 + (kt << 7) + (kk2 << 5) + (fg << 3));
                    oacc[mi][n2] = MFMA16(pa, vf, oacc[mi][n2]);
                }
            }
            __builtin_amdgcn_s_setprio(0);
        }
    }

    #pragma unroll
    for (int mi = 0; mi < 2; ++mi)
        #pragma unroll
        for (int n2 = 0; n2 < 4; ++n2)
            #pragma unroll
            for (int r = 0; r < 4; ++r) {
                const int q = qbase + (mi << 4) + fg4 + r;
                *(__bf16*)&Hb[(((size_t)q * 2 + b) << 10) + (h << 6) + (n2 << 4) + fr] =
                    (__bf16)oacc[mi][n2][r];
            }
}

// ---------------------------------------------------------------------------
// out_proj: out = H @ Wob^T + bo (fp32), double-buffered BK=32.
// ---------------------------------------------------------------------------
__global__ __launch_bounds__(256) void out_proj(
    const unsigned short* __restrict__ Hb, const unsigned short* __restrict__ Wob,
    const float* __restrict__ bo, float* __restrict__ out)
{
    __shared__ unsigned short As[2][128 * 32];
    __shared__ unsigned short Bs[2][128 * 32];

    const int t = threadIdx.x, lane = t & 63, w = t >> 6;
    const int wm = w >> 1, wn = w & 1;
    const int bm = blockIdx.x * 128, bn = blockIdx.y * 128;
    const int fr = lane & 15, fg = lane >> 4;

    const unsigned short* Ap = Hb + (size_t)bm * HID;
    const unsigned short* Bp = Wob + (size_t)bn * HID;

    f32x4 acc[4][4] = {};
    GEMM_BODY(Ap, Bp)

    #pragma unroll
    for (int n = 0; n < 4; ++n) {
        const int gc = bn + wn * 64 + n * 16 + fr;
        const float bb = bo[gc];
        #pragma unroll
        for (int m = 0; m < 4; ++m)
            #pragma unroll
            for (int r = 0; r < 4; ++r) {
                const int gr = bm + wm * 64 + m * 16 + fg * 4 + r;
                out[(size_t)gr * HID + gc] = acc[m][n][r] + bb;
            }
    }
}

// ---------------------------------------------------------------------------
extern "C" void kernel_launch(void* const* d_in, const int* in_sizes, int n_in,
                              void* d_out, int out_size, void* d_ws, size_t ws_size,
                              hipStream_t stream)
{
    (void)in_sizes; (void)n_in; (void)out_size;

    const float* query = (const float*)d_in[0];
    const float* key   = (const float*)d_in[1];
    const float* value = (const float*)d_in[2];
    const float* bq    = (const float*)d_in[4];
    const float* bk    = (const float*)d_in[6];
    const float* bv    = (const float*)d_in[8];
    const float* Wo    = (const float*)d_in[9];
    const float* bo    = (const float*)d_in[10];

    float* out0 = (float*)d_out;
    float* attn = out0 + (size_t)MROWS * HID;

    if (ws_size < (size_t)32 * 1024 * 1024) return;
    const size_t nbuf = (size_t)MROWS * HID;            // 4M bf16 = 8MB
    unsigned short* Qb = (unsigned short*)d_ws;         // [0, 8MB)
    unsigned short* Kb = Qb + nbuf;                     // [8, 16MB)
    unsigned short* Vb = Kb + nbuf;                     // [16, 24MB) -> Hb after vtrans
    unsigned short* Vt = Vb + nbuf;                     // [24, 32MB)
    unsigned short* Hb = Vb;
    unsigned short* Wob = Qb;                           // Qb dead after attn2

    unsigned short* Sc = (unsigned short*)attn;         // scratch inside attn area (30MB)

    conv6<<<dim3(2048, 6), 256, 0, stream>>>(query, key, value,
                                             (const float*)d_in[3], (const float*)d_in[5],
                                             (const float*)d_in[7], Sc);
    qkv_gemm<<<dim3(32, 8, 3), 256, 0, stream>>>(Sc, bq, bk, bv, Qb, Kb, Vb);
    vtrans<<<dim3(32, NHEAD, NBATCH), 256, 0, stream>>>(Vb, Vt);
    attn2<<<dim3(16, NHEAD, NBATCH), 256, 0, stream>>>(Qb, Kb, Vt, attn, Hb);
    wconv<<<dim3(512), 256, 0, stream>>>(Wo, Wob);
    out_proj<<<dim3(32, 8), 256, 0, stream>>>(Hb, Wob, bo, out0);
}